// Round 10
// baseline (553.869 us; speedup 1.0000x reference)
//
#include <hip/hip_runtime.h>
#include <hip/hip_bf16.h>
#include <stdint.h>

// ---------------- problem constants ----------------
#define N_NODES   20000
#define N_EDGES   320000
#define E_TOT     (N_EDGES + N_NODES)   // 340000 incl. self-loops
#define IN_CH     256
#define HID       128
#define HEADS     4
#define OUT_CH    200
#define NUM_GRAPHS 64
#define M_PAD     20096                 // 157 * 128

typedef __bf16 bf16_t;
typedef __bf16 bf16x8 __attribute__((ext_vector_type(8)));
typedef __bf16 bf16x2 __attribute__((ext_vector_type(2)));
typedef float  f32x4  __attribute__((ext_vector_type(4)));

// ---------------- inline dtype detection (per-wave, ~200 cycles) ----------------
__device__ __forceinline__ bool detect_bf16(const unsigned short* __restrict__ xu16) {
  int lane = threadIdx.x & 63;
  unsigned short v = xu16[2 * lane];
  int e = (v >> 7) & 0xff;
  unsigned long long b = __ballot(e >= 90 && e <= 160);
  return __popcll(b) >= 40;
}
__device__ __forceinline__ bool detect_i64(const unsigned* __restrict__ eidx) {
  int lane = threadIdx.x & 63;
  unsigned long long b = __ballot(eidx[2 * lane + 1] == 0u);
  return __popcll(b) >= 32;
}

// ---------------- prep: weights cvt/transpose + small arrays + int cvt + deg hist ----
struct SmallCvt {
  const void* src[11];
  bf16_t* dst[11];
  int n[11];
};

__global__ void prep(const void* __restrict__ W1, const void* __restrict__ W2,
                     const void* __restrict__ W3, bf16_t* __restrict__ W1T,
                     bf16_t* __restrict__ W2T, bf16_t* __restrict__ W3T,
                     SmallCvt tab, const unsigned short* __restrict__ xu16,
                     const int* __restrict__ eidx, const int* __restrict__ batch,
                     int* __restrict__ esrc, int* __restrict__ edst,
                     int* __restrict__ b32, int* __restrict__ deg) {
  bool isbf = detect_bf16(xu16);
  bool i64  = detect_i64((const unsigned*)eidx);
  int i = blockIdx.x * 256 + threadIdx.x;
  // ---- int convert + degree histogram (random bins; round-4 lesson: never
  //      atomic into few sorted bins)
  if (i < N_EDGES) {
    int s = i64 ? eidx[2 * i] : eidx[i];
    int d = i64 ? eidx[2 * (N_EDGES + i)] : eidx[N_EDGES + i];
    esrc[i] = s;
    edst[i] = d;
    atomicAdd(&deg[d], 1);
  }
  if (i < N_NODES) {
    b32[i] = i64 ? batch[2 * i] : batch[i];
    atomicAdd(&deg[i], 1);                           // self-loop
  }
  // ---- weight transposes + small arrays
  if (i < 131072) {                                  // W1 [256,512] -> W1T [512,256]
    int k = i >> 9, nn = i & 511;
    bf16_t v = isbf ? ((const bf16_t*)W1)[i] : (bf16_t)((const float*)W1)[i];
    W1T[(size_t)nn * 256 + k] = v;
  } else if (i < 131072 + 262144) {                  // W2 [512,512]
    int i2 = i - 131072;
    int k = i2 >> 9, nn = i2 & 511;
    bf16_t v = isbf ? ((const bf16_t*)W2)[i2] : (bf16_t)((const float*)W2)[i2];
    W2T[(size_t)nn * 512 + k] = v;
  } else if (i < 131072 + 262144 + 65536) {          // W3 [512,128]
    int i3 = i - 131072 - 262144;
    int k = i3 >> 7, nn = i3 & 127;
    bf16_t v = isbf ? ((const bf16_t*)W3)[i3] : (bf16_t)((const float*)W3)[i3];
    W3T[(size_t)nn * 512 + k] = v;
  } else {                                           // small arrays
    int j = i - 458752;
    for (int s = 0; s < 11; ++s) {
      if (j < tab.n[s]) {
        tab.dst[s][j] = isbf ? ((const bf16_t*)tab.src[s])[j]
                             : (bf16_t)((const float*)tab.src[s])[j];
        break;
      }
      j -= tab.n[s];
    }
  }
}

// ---------------- CSR offsets: single-block scan, per-thread register tiles ----------
__launch_bounds__(1024)
__global__ void scan_deg_block(const int* __restrict__ deg, int* __restrict__ off,
                               int* __restrict__ cursor) {
  const int PT = 20;                   // 1024*20 = 20480 >= N_NODES
  int t = threadIdx.x;
  int lane = t & 63, wid = t >> 6;     // 16 waves
  int base = t * PT;
  int v[PT];
  int s = 0;
#pragma unroll
  for (int j = 0; j < PT; ++j) {
    int i = base + j;
    v[j] = (i < N_NODES) ? deg[i] : 0;
    s += v[j];
  }
  int x = s;                           // wave inclusive scan
  for (int d = 1; d < 64; d <<= 1) {
    int y = __shfl_up(x, d);
    if (lane >= d) x += y;
  }
  __shared__ int wsum[16];
  if (lane == 63) wsum[wid] = x;
  __syncthreads();
  if (t < 16) {
    int y = wsum[t];
    for (int d = 1; d < 16; d <<= 1) {
      int z = __shfl_up(y, d);
      if (t >= d) y += z;
    }
    wsum[t] = y;
  }
  __syncthreads();
  int run = (wid > 0 ? wsum[wid - 1] : 0) + (x - s);  // exclusive prefix
#pragma unroll
  for (int j = 0; j < PT; ++j) {
    int i = base + j;
    if (i < N_NODES) { off[i] = run; cursor[i] = 0; run += v[j]; }
  }
  if (t == 1023) off[N_NODES] = run;
}

__global__ void scatter_kernel(const int* __restrict__ esrc, const int* __restrict__ edst,
                               const int* __restrict__ off, int* __restrict__ cursor,
                               int* __restrict__ csr_src) {
  int e = blockIdx.x * 256 + threadIdx.x;
  if (e >= E_TOT) return;
  int s, d;
  if (e < N_EDGES) { s = esrc[e]; d = edst[e]; } else { s = d = e - N_EDGES; }
  int pos = off[d] + atomicAdd(&cursor[d], 1);
  csr_src[pos] = s;
}

// ---------------- MFMA GEMM + fused alpha epilogue ----------------
template<bool MAYBE_F32>
__launch_bounds__(256)
__global__ void gemm_bf16(const void* __restrict__ Av, const bf16_t* __restrict__ BT,
                          bf16_t* __restrict__ C, int M, int N, int K,
                          const bf16_t* __restrict__ a_src, const bf16_t* __restrict__ a_dst,
                          float* __restrict__ as, float* __restrict__ ad, int H) {
  bool isbf = MAYBE_F32 ? detect_bf16((const unsigned short*)Av) : true;
  const bf16_t* A  = (const bf16_t*)Av;
  const float*  Af = (const float*)Av;
  __shared__ bf16_t As[128 * 32];
  __shared__ bf16_t Bs[128 * 32];
  __shared__ float sred[2][128];
  __shared__ float dred[2][128];
  const int tid  = threadIdx.x;
  const int lane = tid & 63;
  const int w    = tid >> 6;
  const int wm   = w & 1, wn = w >> 1;
  const int bm   = blockIdx.x * 128;
  const int bn   = blockIdx.y * 128;
  const int quad = lane >> 4;
  const int l16  = lane & 15;
  const int hd   = bn >> 7;            // head owned by this block column

  f32x4 zero = {0.f, 0.f, 0.f, 0.f};
  f32x4 acc[4][4];
  for (int i = 0; i < 4; ++i)
    for (int j = 0; j < 4; ++j) acc[i][j] = zero;

  const int c0 = tid, c1 = tid + 256;         // 16B chunks of the 128x32 tile
  const int r0 = c0 >> 2, s0 = c0 & 3;
  const int r1 = c1 >> 2, s1 = c1 & 3;
  int ga0 = bm + r0; if (ga0 > M - 1) ga0 = M - 1;   // clamp: garbage rows never stored
  int ga1 = bm + r1; if (ga1 > M - 1) ga1 = M - 1;

  for (int k0 = 0; k0 < K; k0 += 32) {
    if (!MAYBE_F32 || isbf) {
      __syncthreads();
      __builtin_amdgcn_global_load_lds(
          (const __attribute__((address_space(1))) void*)(A + (size_t)ga0 * K + k0 + s0 * 8),
          (__attribute__((address_space(3))) void*)(As + (size_t)(w * 64) * 8), 16, 0, 0);
      __builtin_amdgcn_global_load_lds(
          (const __attribute__((address_space(1))) void*)(BT + (size_t)(bn + r0) * K + k0 + s0 * 8),
          (__attribute__((address_space(3))) void*)(Bs + (size_t)(w * 64) * 8), 16, 0, 0);
      __builtin_amdgcn_global_load_lds(
          (const __attribute__((address_space(1))) void*)(A + (size_t)ga1 * K + k0 + s1 * 8),
          (__attribute__((address_space(3))) void*)(As + (size_t)(256 + w * 64) * 8), 16, 0, 0);
      __builtin_amdgcn_global_load_lds(
          (const __attribute__((address_space(1))) void*)(BT + (size_t)(bn + r1) * K + k0 + s1 * 8),
          (__attribute__((address_space(3))) void*)(Bs + (size_t)(256 + w * 64) * 8), 16, 0, 0);
      __syncthreads();
    } else {
      bf16x8 va0, va1;
      const float* p0 = Af + (size_t)ga0 * K + k0 + s0 * 8;
      const float* p1 = Af + (size_t)ga1 * K + k0 + s1 * 8;
      f32x4 l0 = *(const f32x4*)p0, h0 = *(const f32x4*)(p0 + 4);
      f32x4 l1 = *(const f32x4*)p1, h1 = *(const f32x4*)(p1 + 4);
      for (int j = 0; j < 4; ++j) {
        va0[j] = (bf16_t)l0[j]; va0[j + 4] = (bf16_t)h0[j];
        va1[j] = (bf16_t)l1[j]; va1[j + 4] = (bf16_t)h1[j];
      }
      bf16x8 vb0 = *(const bf16x8*)(BT + (size_t)(bn + r0) * K + k0 + s0 * 8);
      bf16x8 vb1 = *(const bf16x8*)(BT + (size_t)(bn + r1) * K + k0 + s1 * 8);
      __syncthreads();
      *(bf16x8*)(As + c0 * 8) = va0;
      *(bf16x8*)(Bs + c0 * 8) = vb0;
      *(bf16x8*)(As + c1 * 8) = va1;
      *(bf16x8*)(Bs + c1 * 8) = vb1;
      __syncthreads();
    }

    bf16x8 af[4], bfr[4];
    for (int mt = 0; mt < 4; ++mt) {
      int m_local = wm * 64 + mt * 16 + l16;
      af[mt] = *(const bf16x8*)(As + m_local * 32 + quad * 8);
    }
    for (int nt = 0; nt < 4; ++nt) {
      int n_local = wn * 64 + nt * 16 + l16;
      bfr[nt] = *(const bf16x8*)(Bs + n_local * 32 + quad * 8);
    }
    for (int mt = 0; mt < 4; ++mt)
      for (int nt = 0; nt < 4; ++nt)
        acc[mt][nt] = __builtin_amdgcn_mfma_f32_16x16x32_bf16(af[mt], bfr[nt], acc[mt][nt], 0, 0, 0);
  }

  // ---- C store.  C/D layout: col=lane&15, row=(lane>>4)*4+r   [m89-verified]
  for (int mt = 0; mt < 4; ++mt) {
    for (int r = 0; r < 4; ++r) {
      int m = bm + wm * 64 + mt * 16 + quad * 4 + r;
      if (m >= M) continue;
      for (int nt = 0; nt < 4; ++nt) {
        int n = bn + wn * 64 + nt * 16 + l16;
        C[(size_t)m * N + n] = (bf16_t)acc[mt][nt][r];
      }
    }
  }

  // ---- fused alpha epilogue: per-row dots over this block's 128 columns
  float av[4], dv[4];
  for (int nt = 0; nt < 4; ++nt) {
    int ch = wn * 64 + nt * 16 + l16;            // channel within head
    av[nt] = (float)a_src[hd * 128 + ch];
    dv[nt] = (float)a_dst[hd * 128 + ch];
  }
  for (int mt = 0; mt < 4; ++mt) {
    for (int r = 0; r < 4; ++r) {
      float s = acc[mt][0][r] * av[0] + acc[mt][1][r] * av[1]
              + acc[mt][2][r] * av[2] + acc[mt][3][r] * av[3];
      float d = acc[mt][0][r] * dv[0] + acc[mt][1][r] * dv[1]
              + acc[mt][2][r] * dv[2] + acc[mt][3][r] * dv[3];
      for (int o = 1; o < 16; o <<= 1) {         // reduce across 16-lane col group
        s += __shfl_xor(s, o);
        d += __shfl_xor(d, o);
      }
      if (l16 == 0) {
        int row_local = wm * 64 + mt * 16 + quad * 4 + r;
        sred[wn][row_local] = s;
        dred[wn][row_local] = d;
      }
    }
  }
  __syncthreads();
  if (tid < 128) {
    int m = bm + tid;
    if (m < M) {
      as[m * H + hd] = sred[0][tid] + sred[1][tid];
      ad[m * H + hd] = dred[0][tid] + dred[1][tid];
    }
  }
}

// ---------------- XCD-sliced fused softmax + aggregation + bias + ELU ----------------
// Round-10: agg was pinned at 2.9 TB/s L3->L2 fill (FETCH 148MB = 8-XCD redundancy
// floor for whole-h gathers).  Slice channels into 64-ch strips; slice = blockIdx %
// SLICES rides the de-facto blockIdx%8 -> XCD round-robin so each XCD's L2 only holds
// its 2.6MB strip (< 4MB L2) -> gathers become L2 hits.  Perf-only heuristic; math
// per slice is bit-identical to the unsliced kernel.
// Wave layout: 1 node/wave, 2 edges/iter (half-wave each, 2 ch/lane), halves combined
// via shfl_xor(32).
template<int C, int SLICES>
__launch_bounds__(256)
__global__ void agg_sliced(const bf16_t* __restrict__ h, const int* __restrict__ off,
                           const int* __restrict__ csr_src, const float* __restrict__ as,
                           const float* __restrict__ ad, const bf16_t* __restrict__ bias,
                           bf16_t* __restrict__ outp, int H) {
  int slice = blockIdx.x % SLICES;
  int grp   = blockIdx.x / SLICES;
  int wave  = threadIdx.x >> 6;
  int n = grp * 4 + wave;
  if (n >= N_NODES) return;
  int lane = threadIdx.x & 63;
  int half = lane >> 5;                    // 0: edge pos, 1: edge pos+1
  int l32  = lane & 31;
  int cbase = slice * 64;
  int hd = cbase >> 7;
  int c = cbase + l32 * 2;                 // 2 channels per lane
  int start = __builtin_amdgcn_readfirstlane(off[n]);
  int end   = __builtin_amdgcn_readfirstlane(off[n + 1]);
  float adv = ad[n * H + hd];
  float a0 = 0.f, a1 = 0.f, den = 0.f;

  for (int pos = start; pos < end; pos += 2) {
    int p = pos + half;
    bool valid = p < end;
    int pc = valid ? p : end - 1;
    int src = csr_src[pc];
    float e = as[src * H + hd] + adv;
    e = e > 0.f ? e : 0.2f * e;            // leaky_relu(0.2)
    float wgt = valid ? __expf(e) : 0.f;
    bf16x2 hv = *(const bf16x2*)(h + (size_t)src * C + c);
    a0 += wgt * (float)hv[0];
    a1 += wgt * (float)hv[1];
    den += wgt;
  }
  // combine the two halves (same channels, disjoint edge subsets)
  a0  += __shfl_xor(a0, 32);
  a1  += __shfl_xor(a1, 32);
  den += __shfl_xor(den, 32);
  if (half == 0) {
    float inv = 1.f / (den + 1e-16f);
    float o0 = a0 * inv + (float)bias[c];
    float o1 = a1 * inv + (float)bias[c + 1];
    o0 = o0 > 0.f ? o0 : expm1f(o0);       // elu
    o1 = o1 > 0.f ? o1 : expm1f(o1);
    bf16x2 ov; ov[0] = (bf16_t)o0; ov[1] = (bf16_t)o1;
    *(bf16x2*)(outp + (size_t)n * C + c) = ov;
  }
}

// ---------------- merged mean-pool + FC: one block per graph, no atomics -------------
__launch_bounds__(256)
__global__ void pool_fc2(const bf16_t* __restrict__ h3, const int* __restrict__ batch,
                         const bf16_t* __restrict__ fcw, const bf16_t* __restrict__ fcb,
                         void* __restrict__ outp, const unsigned short* __restrict__ xu16) {
  bool isbf = detect_bf16(xu16);
  int g = blockIdx.x;
  int lo = 0, hi = N_NODES;
  while (lo < hi) { int mid = (lo + hi) >> 1; if (batch[mid] < g) lo = mid + 1; else hi = mid; }
  int start = lo;
  hi = N_NODES;
  while (lo < hi) { int mid = (lo + hi) >> 1; if (batch[mid] < g + 1) lo = mid + 1; else hi = mid; }
  int end = lo, cnt = end - start;

  int t = threadIdx.x;
  int wave = t >> 6, lane = t & 63;
  int c0 = lane * 2;
  float a0 = 0.f, a1 = 0.f;
  for (int n = start + wave; n < end; n += 4) {     // independent coalesced loads
    bf16x2 v = *(const bf16x2*)(h3 + (size_t)n * HID + c0);
    a0 += (float)v[0];
    a1 += (float)v[1];
  }
  __shared__ float red[4][HID];
  red[wave][c0] = a0;
  red[wave][c0 + 1] = a1;
  __syncthreads();
  __shared__ float pooled[HID];
  if (t < HID) {
    float s = red[0][t] + red[1][t] + red[2][t] + red[3][t];
    pooled[t] = s / (float)(cnt > 0 ? cnt : 1);
  }
  __syncthreads();
  if (t < OUT_CH) {
    float a = (float)fcb[t];
    for (int c = 0; c < HID; ++c) a += pooled[c] * (float)fcw[c * OUT_CH + t];
    if (isbf) ((bf16_t*)outp)[g * OUT_CH + t] = (bf16_t)a;
    else      ((float*)outp)[g * OUT_CH + t] = a;
  }
}

// ---------------- launcher ----------------
extern "C" void kernel_launch(void* const* d_in, const int* in_sizes, int n_in,
                              void* d_out, int out_size, void* d_ws, size_t ws_size,
                              hipStream_t stream) {
  const void* x    = d_in[0];
  const void* eidx = d_in[1];
  const void* batch= d_in[2];
  const void* W1   = d_in[3];
  const void* a_s1 = d_in[4];
  const void* a_d1 = d_in[5];
  const void* b1   = d_in[6];
  const void* W2   = d_in[7];
  const void* a_s2 = d_in[8];
  const void* a_d2 = d_in[9];
  const void* b2   = d_in[10];
  const void* W3   = d_in[11];
  const void* a_s3 = d_in[12];
  const void* a_d3 = d_in[13];
  const void* b3   = d_in[14];
  const void* fcw  = d_in[15];
  const void* fcb  = d_in[16];
  const unsigned short* xu16 = (const unsigned short*)x;

  char* p = (char*)d_ws;
  auto carve = [&](size_t nbytes) { char* r = p; p += (nbytes + 255) & ~(size_t)255; return r; };
  bf16_t*   W1T    = (bf16_t*)carve((size_t)512 * 256 * 2);
  bf16_t*   W2T    = (bf16_t*)carve((size_t)512 * 512 * 2);
  bf16_t*   W3T    = (bf16_t*)carve((size_t)128 * 512 * 2);
  bf16_t*   hA     = (bf16_t*)carve((size_t)M_PAD * 512 * 2);
  bf16_t*   hB     = (bf16_t*)carve((size_t)M_PAD * 512 * 2);
  bf16_t*   sm     = (bf16_t*)carve((size_t)32768 * 2);
  bf16_t *as1b = sm, *ad1b = sm + 512, *b1b = sm + 1024,
         *as2b = sm + 1536, *ad2b = sm + 2048, *b2b = sm + 2560,
         *as3b = sm + 3072, *ad3b = sm + 3200, *b3b = sm + 3328,
         *fcwb = sm + 3456, *fcbb = sm + 29056;
  float*    asb    = (float*)carve((size_t)N_NODES * 4 * 4);
  float*    adb    = (float*)carve((size_t)N_NODES * 4 * 4);
  int*      deg    = (int*)carve((size_t)N_NODES * 4);
  int*      off    = (int*)carve((size_t)(N_NODES + 1) * 4);
  int*      cursor = (int*)carve((size_t)N_NODES * 4);
  int*      csr_src= (int*)carve((size_t)E_TOT * 4);
  int*      esrc32 = (int*)carve((size_t)N_EDGES * 4);
  int*      edst32 = (int*)carve((size_t)N_EDGES * 4);
  int*      bat32  = (int*)carve((size_t)N_NODES * 4);

  dim3 b256(256);
  const int NGRP = (N_NODES + 3) / 4;   // node groups of 4 (1 node/wave)

  SmallCvt tab;
  const void* srcs[11] = {a_s1, a_d1, b1, a_s2, a_d2, b2, a_s3, a_d3, b3, fcw, fcb};
  bf16_t* dsts[11] = {as1b, ad1b, b1b, as2b, ad2b, b2b, as3b, ad3b, b3b, fcwb, fcbb};
  int ns[11] = {512, 512, 512, 512, 512, 512, 128, 128, 128, 25600, 200};
  for (int i = 0; i < 11; ++i) { tab.src[i] = srcs[i]; tab.dst[i] = dsts[i]; tab.n[i] = ns[i]; }

  hipMemsetAsync(deg, 0, (size_t)N_NODES * 4, stream);
  prep<<<dim3((458752 + 29256 + 255) / 256), b256, 0, stream>>>(
      W1, W2, W3, W1T, W2T, W3T, tab, xu16,
      (const int*)eidx, (const int*)batch, esrc32, edst32, bat32, deg);

  // CSR-by-dst (src-only payload; reused by all 3 layers)
  scan_deg_block<<<dim3(1), dim3(1024), 0, stream>>>(deg, off, cursor);
  scatter_kernel<<<dim3((E_TOT + 255) / 256), b256, 0, stream>>>(esrc32, edst32, off, cursor, csr_src);

  // ---- layer 1: x (raw, dtype-detected in-kernel) -> hA[.,512] + alpha -> agg -> hB
  gemm_bf16<true><<<dim3(157, 4), b256, 0, stream>>>(x, W1T, hA, N_NODES, 512, 256,
                                                     as1b, ad1b, asb, adb, 4);
  agg_sliced<512, 8><<<dim3(NGRP * 8), b256, 0, stream>>>(hA, off, csr_src, asb, adb, b1b, hB, 4);

  // ---- layer 2
  gemm_bf16<false><<<dim3(157, 4), b256, 0, stream>>>(hB, W2T, hA, N_NODES, 512, 512,
                                                      as2b, ad2b, asb, adb, 4);
  agg_sliced<512, 8><<<dim3(NGRP * 8), b256, 0, stream>>>(hA, off, csr_src, asb, adb, b2b, hB, 4);

  // ---- layer 3
  gemm_bf16<false><<<dim3(157, 1), b256, 0, stream>>>(hB, W3T, hA, N_NODES, 128, 512,
                                                      as3b, ad3b, asb, adb, 1);
  agg_sliced<128, 2><<<dim3(NGRP * 2), b256, 0, stream>>>(hA, off, csr_src, asb, adb, b3b, hB, 1);

  // ---- merged mean-pool + FC
  pool_fc2<<<dim3(NUM_GRAPHS), b256, 0, stream>>>(hB, bat32, fcwb, fcbb, d_out, xu16);
}

// Round 11
// 364.496 us; speedup vs baseline: 1.5195x; 1.5195x over previous
//
#include <hip/hip_runtime.h>
#include <hip/hip_bf16.h>
#include <stdint.h>

// ---------------- problem constants ----------------
#define N_NODES   20000
#define N_EDGES   320000
#define E_TOT     (N_EDGES + N_NODES)   // 340000 incl. self-loops
#define IN_CH     256
#define HID       128
#define HEADS     4
#define OUT_CH    200
#define NUM_GRAPHS 64
#define M_PAD     20096                 // 157 * 128

typedef __bf16 bf16_t;
typedef __bf16 bf16x8 __attribute__((ext_vector_type(8)));
typedef __bf16 bf16x2 __attribute__((ext_vector_type(2)));
typedef float  f32x4  __attribute__((ext_vector_type(4)));

// ---------------- inline dtype detection (per-wave, ~200 cycles) ----------------
__device__ __forceinline__ bool detect_bf16(const unsigned short* __restrict__ xu16) {
  int lane = threadIdx.x & 63;
  unsigned short v = xu16[2 * lane];
  int e = (v >> 7) & 0xff;
  unsigned long long b = __ballot(e >= 90 && e <= 160);
  return __popcll(b) >= 40;
}
__device__ __forceinline__ bool detect_i64(const unsigned* __restrict__ eidx) {
  int lane = threadIdx.x & 63;
  unsigned long long b = __ballot(eidx[2 * lane + 1] == 0u);
  return __popcll(b) >= 32;
}

// ---------------- prep: weights cvt/transpose + small arrays + int cvt + deg hist ----
struct SmallCvt {
  const void* src[11];
  bf16_t* dst[11];
  int n[11];
};

__global__ void prep(const void* __restrict__ W1, const void* __restrict__ W2,
                     const void* __restrict__ W3, bf16_t* __restrict__ W1T,
                     bf16_t* __restrict__ W2T, bf16_t* __restrict__ W3T,
                     SmallCvt tab, const unsigned short* __restrict__ xu16,
                     const int* __restrict__ eidx, const int* __restrict__ batch,
                     int* __restrict__ esrc, int* __restrict__ edst,
                     int* __restrict__ b32, int* __restrict__ deg) {
  bool isbf = detect_bf16(xu16);
  bool i64  = detect_i64((const unsigned*)eidx);
  int i = blockIdx.x * 256 + threadIdx.x;
  if (i < N_EDGES) {
    int s = i64 ? eidx[2 * i] : eidx[i];
    int d = i64 ? eidx[2 * (N_EDGES + i)] : eidx[N_EDGES + i];
    esrc[i] = s;
    edst[i] = d;
    atomicAdd(&deg[d], 1);          // random bins; round-4 lesson: never few sorted bins
  }
  if (i < N_NODES) {
    b32[i] = i64 ? batch[2 * i] : batch[i];
    atomicAdd(&deg[i], 1);          // self-loop
  }
  if (i < 131072) {                 // W1 [256,512] -> W1T [512,256]
    int k = i >> 9, nn = i & 511;
    bf16_t v = isbf ? ((const bf16_t*)W1)[i] : (bf16_t)((const float*)W1)[i];
    W1T[(size_t)nn * 256 + k] = v;
  } else if (i < 131072 + 262144) { // W2 [512,512]
    int i2 = i - 131072;
    int k = i2 >> 9, nn = i2 & 511;
    bf16_t v = isbf ? ((const bf16_t*)W2)[i2] : (bf16_t)((const float*)W2)[i2];
    W2T[(size_t)nn * 512 + k] = v;
  } else if (i < 131072 + 262144 + 65536) {  // W3 [512,128]
    int i3 = i - 131072 - 262144;
    int k = i3 >> 7, nn = i3 & 127;
    bf16_t v = isbf ? ((const bf16_t*)W3)[i3] : (bf16_t)((const float*)W3)[i3];
    W3T[(size_t)nn * 512 + k] = v;
  } else {
    int j = i - 458752;
    for (int s = 0; s < 11; ++s) {
      if (j < tab.n[s]) {
        tab.dst[s][j] = isbf ? ((const bf16_t*)tab.src[s])[j]
                             : (bf16_t)((const float*)tab.src[s])[j];
        break;
      }
      j -= tab.n[s];
    }
  }
}

// ---------------- CSR offsets: single-block scan, per-thread register tiles ----------
__launch_bounds__(1024)
__global__ void scan_deg_block(const int* __restrict__ deg, int* __restrict__ off,
                               int* __restrict__ cursor) {
  const int PT = 20;                   // 1024*20 = 20480 >= N_NODES
  int t = threadIdx.x;
  int lane = t & 63, wid = t >> 6;     // 16 waves
  int base = t * PT;
  int v[PT];
  int s = 0;
#pragma unroll
  for (int j = 0; j < PT; ++j) {
    int i = base + j;
    v[j] = (i < N_NODES) ? deg[i] : 0;
    s += v[j];
  }
  int x = s;
  for (int d = 1; d < 64; d <<= 1) {
    int y = __shfl_up(x, d);
    if (lane >= d) x += y;
  }
  __shared__ int wsum[16];
  if (lane == 63) wsum[wid] = x;
  __syncthreads();
  if (t < 16) {
    int y = wsum[t];
    for (int d = 1; d < 16; d <<= 1) {
      int z = __shfl_up(y, d);
      if (t >= d) y += z;
    }
    wsum[t] = y;
  }
  __syncthreads();
  int run = (wid > 0 ? wsum[wid - 1] : 0) + (x - s);
#pragma unroll
  for (int j = 0; j < PT; ++j) {
    int i = base + j;
    if (i < N_NODES) { off[i] = run; cursor[i] = 0; run += v[j]; }
  }
  if (t == 1023) off[N_NODES] = run;
}

__global__ void scatter_kernel(const int* __restrict__ esrc, const int* __restrict__ edst,
                               const int* __restrict__ off, int* __restrict__ cursor,
                               int* __restrict__ csr_src) {
  int e = blockIdx.x * 256 + threadIdx.x;
  if (e >= E_TOT) return;
  int s, d;
  if (e < N_EDGES) { s = esrc[e]; d = edst[e]; } else { s = d = e - N_EDGES; }
  int pos = off[d] + atomicAdd(&cursor[d], 1);
  csr_src[pos] = s;
}

// ---------------- MFMA GEMM + fused alpha epilogue, XCD-grouped grid ----------------
// 1-D grid; same-bm blocks (all bn) share id%8 -> same XCD (round-10: %8->XCD verified
// via FETCH collapse) so the shared A-tile is L2-filled once per XCD, not NBN times.
// NBN = N/128.  bm padded to multiple of 8; clamps/guards make extra blocks harmless.
template<bool MAYBE_F32, int NBN>
__launch_bounds__(256)
__global__ void gemm_bf16(const void* __restrict__ Av, const bf16_t* __restrict__ BT,
                          bf16_t* __restrict__ C, int M, int N, int K,
                          const bf16_t* __restrict__ a_src, const bf16_t* __restrict__ a_dst,
                          float* __restrict__ as, float* __restrict__ ad, int H) {
  bool isbf = MAYBE_F32 ? detect_bf16((const unsigned short*)Av) : true;
  const bf16_t* A  = (const bf16_t*)Av;
  const float*  Af = (const float*)Av;
  __shared__ bf16_t As[128 * 32];
  __shared__ bf16_t Bs[128 * 32];
  __shared__ float sred[2][128];
  __shared__ float dred[2][128];
  const int tid  = threadIdx.x;
  const int lane = tid & 63;
  const int w    = tid >> 6;
  const int wm   = w & 1, wn = w >> 1;
  // XCD-grouped decode: id%8 == bm%8
  const int id   = blockIdx.x;
  const int bmq  = id / (8 * NBN);
  const int rem  = id % (8 * NBN);
  const int bm   = (bmq * 8 + (rem & 7)) * 128;
  const int bn   = (rem >> 3) * 128;
  const int quad = lane >> 4;
  const int l16  = lane & 15;
  const int hd   = bn >> 7;            // head owned by this block column

  f32x4 zero = {0.f, 0.f, 0.f, 0.f};
  f32x4 acc[4][4];
  for (int i = 0; i < 4; ++i)
    for (int j = 0; j < 4; ++j) acc[i][j] = zero;

  const int c0 = tid, c1 = tid + 256;         // 16B chunks of the 128x32 tile
  const int r0 = c0 >> 2, s0 = c0 & 3;
  const int r1 = c1 >> 2, s1 = c1 & 3;
  int ga0 = bm + r0; if (ga0 > M - 1) ga0 = M - 1;   // clamp: garbage rows never stored
  int ga1 = bm + r1; if (ga1 > M - 1) ga1 = M - 1;

  for (int k0 = 0; k0 < K; k0 += 32) {
    if (!MAYBE_F32 || isbf) {
      __syncthreads();
      __builtin_amdgcn_global_load_lds(
          (const __attribute__((address_space(1))) void*)(A + (size_t)ga0 * K + k0 + s0 * 8),
          (__attribute__((address_space(3))) void*)(As + (size_t)(w * 64) * 8), 16, 0, 0);
      __builtin_amdgcn_global_load_lds(
          (const __attribute__((address_space(1))) void*)(BT + (size_t)(bn + r0) * K + k0 + s0 * 8),
          (__attribute__((address_space(3))) void*)(Bs + (size_t)(w * 64) * 8), 16, 0, 0);
      __builtin_amdgcn_global_load_lds(
          (const __attribute__((address_space(1))) void*)(A + (size_t)ga1 * K + k0 + s1 * 8),
          (__attribute__((address_space(3))) void*)(As + (size_t)(256 + w * 64) * 8), 16, 0, 0);
      __builtin_amdgcn_global_load_lds(
          (const __attribute__((address_space(1))) void*)(BT + (size_t)(bn + r1) * K + k0 + s1 * 8),
          (__attribute__((address_space(3))) void*)(Bs + (size_t)(256 + w * 64) * 8), 16, 0, 0);
      __syncthreads();
    } else {
      bf16x8 va0, va1;
      const float* p0 = Af + (size_t)ga0 * K + k0 + s0 * 8;
      const float* p1 = Af + (size_t)ga1 * K + k0 + s1 * 8;
      f32x4 l0 = *(const f32x4*)p0, h0 = *(const f32x4*)(p0 + 4);
      f32x4 l1 = *(const f32x4*)p1, h1 = *(const f32x4*)(p1 + 4);
      for (int j = 0; j < 4; ++j) {
        va0[j] = (bf16_t)l0[j]; va0[j + 4] = (bf16_t)h0[j];
        va1[j] = (bf16_t)l1[j]; va1[j + 4] = (bf16_t)h1[j];
      }
      bf16x8 vb0 = *(const bf16x8*)(BT + (size_t)(bn + r0) * K + k0 + s0 * 8);
      bf16x8 vb1 = *(const bf16x8*)(BT + (size_t)(bn + r1) * K + k0 + s1 * 8);
      __syncthreads();
      *(bf16x8*)(As + c0 * 8) = va0;
      *(bf16x8*)(Bs + c0 * 8) = vb0;
      *(bf16x8*)(As + c1 * 8) = va1;
      *(bf16x8*)(Bs + c1 * 8) = vb1;
      __syncthreads();
    }

    bf16x8 af[4], bfr[4];
    for (int mt = 0; mt < 4; ++mt) {
      int m_local = wm * 64 + mt * 16 + l16;
      af[mt] = *(const bf16x8*)(As + m_local * 32 + quad * 8);
    }
    for (int nt = 0; nt < 4; ++nt) {
      int n_local = wn * 64 + nt * 16 + l16;
      bfr[nt] = *(const bf16x8*)(Bs + n_local * 32 + quad * 8);
    }
    for (int mt = 0; mt < 4; ++mt)
      for (int nt = 0; nt < 4; ++nt)
        acc[mt][nt] = __builtin_amdgcn_mfma_f32_16x16x32_bf16(af[mt], bfr[nt], acc[mt][nt], 0, 0, 0);
  }

  // ---- C store.  C/D layout: col=lane&15, row=(lane>>4)*4+r   [m89-verified]
  for (int mt = 0; mt < 4; ++mt) {
    for (int r = 0; r < 4; ++r) {
      int m = bm + wm * 64 + mt * 16 + quad * 4 + r;
      if (m >= M) continue;
      for (int nt = 0; nt < 4; ++nt) {
        int n = bn + wn * 64 + nt * 16 + l16;
        C[(size_t)m * N + n] = (bf16_t)acc[mt][nt][r];
      }
    }
  }

  // ---- fused alpha epilogue: per-row dots over this block's 128 columns
  float av[4], dv[4];
  for (int nt = 0; nt < 4; ++nt) {
    int ch = wn * 64 + nt * 16 + l16;            // channel within head
    av[nt] = (float)a_src[hd * 128 + ch];
    dv[nt] = (float)a_dst[hd * 128 + ch];
  }
  for (int mt = 0; mt < 4; ++mt) {
    for (int r = 0; r < 4; ++r) {
      float s = acc[mt][0][r] * av[0] + acc[mt][1][r] * av[1]
              + acc[mt][2][r] * av[2] + acc[mt][3][r] * av[3];
      float d = acc[mt][0][r] * dv[0] + acc[mt][1][r] * dv[1]
              + acc[mt][2][r] * dv[2] + acc[mt][3][r] * dv[3];
      for (int o = 1; o < 16; o <<= 1) {
        s += __shfl_xor(s, o);
        d += __shfl_xor(d, o);
      }
      if (l16 == 0) {
        int row_local = wm * 64 + mt * 16 + quad * 4 + r;
        sred[wn][row_local] = s;
        dred[wn][row_local] = d;
      }
    }
  }
  __syncthreads();
  if (tid < 128) {
    int m = bm + tid;
    if (m < M) {
      as[m * H + hd] = sred[0][tid] + sred[1][tid];
      ad[m * H + hd] = dred[0][tid] + dred[1][tid];
    }
  }
}

// ---------------- fused softmax + aggregation + bias + ELU (round-9 form) ------------
// Reverted from XCD slicing (round-10: FETCH 148->18.8MB but 8x per-edge scalar
// overhead made it VALU-bound, 52->138us).  This form is the measured local floor.
template<int CPL>
__launch_bounds__(256)
__global__ void agg_fused(const bf16_t* __restrict__ h, const int* __restrict__ off,
                          const int* __restrict__ csr_src, const float* __restrict__ as,
                          const float* __restrict__ ad, const bf16_t* __restrict__ bias,
                          bf16_t* __restrict__ outp, int H) {
  typedef __bf16 vec_t __attribute__((ext_vector_type(CPL)));
  const int C = CPL * 64;
  int lane = threadIdx.x & 63;
  int n = blockIdx.x * 4 + (threadIdx.x >> 6);
  if (n >= N_NODES) return;
  int start = __builtin_amdgcn_readfirstlane(off[n]);
  int end   = __builtin_amdgcn_readfirstlane(off[n + 1]);
  int c0 = lane * CPL;
  int hd = c0 >> 7;
  float adv = ad[n * H + hd];
  float acc[CPL];
  for (int j = 0; j < CPL; ++j) acc[j] = 0.f;
  float den = 0.f;

  int pos = start;
  for (; pos + 3 < end; pos += 4) {
    int s0 = __builtin_amdgcn_readfirstlane(csr_src[pos]);
    int s1 = __builtin_amdgcn_readfirstlane(csr_src[pos + 1]);
    int s2 = __builtin_amdgcn_readfirstlane(csr_src[pos + 2]);
    int s3 = __builtin_amdgcn_readfirstlane(csr_src[pos + 3]);
    vec_t hv0 = *(const vec_t*)(h + (size_t)s0 * C + c0);
    vec_t hv1 = *(const vec_t*)(h + (size_t)s1 * C + c0);
    vec_t hv2 = *(const vec_t*)(h + (size_t)s2 * C + c0);
    vec_t hv3 = *(const vec_t*)(h + (size_t)s3 * C + c0);
    float e0 = as[s0 * H + hd] + adv; e0 = e0 > 0.f ? e0 : 0.2f * e0;
    float e1 = as[s1 * H + hd] + adv; e1 = e1 > 0.f ? e1 : 0.2f * e1;
    float e2 = as[s2 * H + hd] + adv; e2 = e2 > 0.f ? e2 : 0.2f * e2;
    float e3 = as[s3 * H + hd] + adv; e3 = e3 > 0.f ? e3 : 0.2f * e3;
    float w0 = __expf(e0), w1 = __expf(e1), w2 = __expf(e2), w3 = __expf(e3);
    den += (w0 + w1) + (w2 + w3);
    for (int j = 0; j < CPL; ++j)
      acc[j] += (w0 * (float)hv0[j] + w1 * (float)hv1[j])
              + (w2 * (float)hv2[j] + w3 * (float)hv3[j]);
  }
  for (; pos < end; ++pos) {
    int s0 = __builtin_amdgcn_readfirstlane(csr_src[pos]);
    vec_t hv0 = *(const vec_t*)(h + (size_t)s0 * C + c0);
    float e0 = as[s0 * H + hd] + adv; e0 = e0 > 0.f ? e0 : 0.2f * e0;
    float w0 = __expf(e0);
    den += w0;
    for (int j = 0; j < CPL; ++j) acc[j] += w0 * (float)hv0[j];
  }

  float inv = 1.f / (den + 1e-16f);
  vec_t ov;
  for (int j = 0; j < CPL; ++j) {
    float o = acc[j] * inv + (float)bias[c0 + j];
    o = o > 0.f ? o : expm1f(o);         // elu
    ov[j] = (bf16_t)o;
  }
  *(vec_t*)(outp + (size_t)n * C + c0) = ov;
}

// ---------------- merged mean-pool + FC: one block per graph, no atomics -------------
__launch_bounds__(256)
__global__ void pool_fc2(const bf16_t* __restrict__ h3, const int* __restrict__ batch,
                         const bf16_t* __restrict__ fcw, const bf16_t* __restrict__ fcb,
                         void* __restrict__ outp, const unsigned short* __restrict__ xu16) {
  bool isbf = detect_bf16(xu16);
  int g = blockIdx.x;
  int lo = 0, hi = N_NODES;
  while (lo < hi) { int mid = (lo + hi) >> 1; if (batch[mid] < g) lo = mid + 1; else hi = mid; }
  int start = lo;
  hi = N_NODES;
  while (lo < hi) { int mid = (lo + hi) >> 1; if (batch[mid] < g + 1) lo = mid + 1; else hi = mid; }
  int end = lo, cnt = end - start;

  int t = threadIdx.x;
  int wave = t >> 6, lane = t & 63;
  int c0 = lane * 2;
  float a0 = 0.f, a1 = 0.f;
  for (int n = start + wave; n < end; n += 4) {
    bf16x2 v = *(const bf16x2*)(h3 + (size_t)n * HID + c0);
    a0 += (float)v[0];
    a1 += (float)v[1];
  }
  __shared__ float red[4][HID];
  red[wave][c0] = a0;
  red[wave][c0 + 1] = a1;
  __syncthreads();
  __shared__ float pooled[HID];
  if (t < HID) {
    float s = red[0][t] + red[1][t] + red[2][t] + red[3][t];
    pooled[t] = s / (float)(cnt > 0 ? cnt : 1);
  }
  __syncthreads();
  if (t < OUT_CH) {
    float a = (float)fcb[t];
    for (int c = 0; c < HID; ++c) a += pooled[c] * (float)fcw[c * OUT_CH + t];
    if (isbf) ((bf16_t*)outp)[g * OUT_CH + t] = (bf16_t)a;
    else      ((float*)outp)[g * OUT_CH + t] = a;
  }
}

// ---------------- launcher ----------------
extern "C" void kernel_launch(void* const* d_in, const int* in_sizes, int n_in,
                              void* d_out, int out_size, void* d_ws, size_t ws_size,
                              hipStream_t stream) {
  const void* x    = d_in[0];
  const void* eidx = d_in[1];
  const void* batch= d_in[2];
  const void* W1   = d_in[3];
  const void* a_s1 = d_in[4];
  const void* a_d1 = d_in[5];
  const void* b1   = d_in[6];
  const void* W2   = d_in[7];
  const void* a_s2 = d_in[8];
  const void* a_d2 = d_in[9];
  const void* b2   = d_in[10];
  const void* W3   = d_in[11];
  const void* a_s3 = d_in[12];
  const void* a_d3 = d_in[13];
  const void* b3   = d_in[14];
  const void* fcw  = d_in[15];
  const void* fcb  = d_in[16];
  const unsigned short* xu16 = (const unsigned short*)x;

  char* p = (char*)d_ws;
  auto carve = [&](size_t nbytes) { char* r = p; p += (nbytes + 255) & ~(size_t)255; return r; };
  bf16_t*   W1T    = (bf16_t*)carve((size_t)512 * 256 * 2);
  bf16_t*   W2T    = (bf16_t*)carve((size_t)512 * 512 * 2);
  bf16_t*   W3T    = (bf16_t*)carve((size_t)128 * 512 * 2);
  bf16_t*   hA     = (bf16_t*)carve((size_t)M_PAD * 512 * 2);
  bf16_t*   hB     = (bf16_t*)carve((size_t)M_PAD * 512 * 2);
  bf16_t*   sm     = (bf16_t*)carve((size_t)32768 * 2);
  bf16_t *as1b = sm, *ad1b = sm + 512, *b1b = sm + 1024,
         *as2b = sm + 1536, *ad2b = sm + 2048, *b2b = sm + 2560,
         *as3b = sm + 3072, *ad3b = sm + 3200, *b3b = sm + 3328,
         *fcwb = sm + 3456, *fcbb = sm + 29056;
  float*    asb    = (float*)carve((size_t)N_NODES * 4 * 4);
  float*    adb    = (float*)carve((size_t)N_NODES * 4 * 4);
  int*      deg    = (int*)carve((size_t)N_NODES * 4);
  int*      off    = (int*)carve((size_t)(N_NODES + 1) * 4);
  int*      cursor = (int*)carve((size_t)N_NODES * 4);
  int*      csr_src= (int*)carve((size_t)E_TOT * 4);
  int*      esrc32 = (int*)carve((size_t)N_EDGES * 4);
  int*      edst32 = (int*)carve((size_t)N_EDGES * 4);
  int*      bat32  = (int*)carve((size_t)N_NODES * 4);

  dim3 b256(256);
  const int NG4 = (N_NODES + 3) / 4;   // wave-per-node grids

  SmallCvt tab;
  const void* srcs[11] = {a_s1, a_d1, b1, a_s2, a_d2, b2, a_s3, a_d3, b3, fcw, fcb};
  bf16_t* dsts[11] = {as1b, ad1b, b1b, as2b, ad2b, b2b, as3b, ad3b, b3b, fcwb, fcbb};
  int ns[11] = {512, 512, 512, 512, 512, 512, 128, 128, 128, 25600, 200};
  for (int i = 0; i < 11; ++i) { tab.src[i] = srcs[i]; tab.dst[i] = dsts[i]; tab.n[i] = ns[i]; }

  hipMemsetAsync(deg, 0, (size_t)N_NODES * 4, stream);
  prep<<<dim3((458752 + 29256 + 255) / 256), b256, 0, stream>>>(
      W1, W2, W3, W1T, W2T, W3T, tab, xu16,
      (const int*)eidx, (const int*)batch, esrc32, edst32, bat32, deg);

  // CSR-by-dst (src-only payload; reused by all 3 layers)
  scan_deg_block<<<dim3(1), dim3(1024), 0, stream>>>(deg, off, cursor);
  scatter_kernel<<<dim3((E_TOT + 255) / 256), b256, 0, stream>>>(esrc32, edst32, off, cursor, csr_src);

  // XCD-grouped 1-D gemm grids: 160 bm slots (157 used) x NBN bn
  const int G4 = 160 * 4, G1 = 160 * 1;

  // ---- layer 1: x (raw, dtype-detected in-kernel) -> hA[.,512] + alpha -> agg -> hB
  gemm_bf16<true, 4><<<dim3(G4), b256, 0, stream>>>(x, W1T, hA, N_NODES, 512, 256,
                                                    as1b, ad1b, asb, adb, 4);
  agg_fused<8><<<dim3(NG4), b256, 0, stream>>>(hA, off, csr_src, asb, adb, b1b, hB, 4);

  // ---- layer 2
  gemm_bf16<false, 4><<<dim3(G4), b256, 0, stream>>>(hB, W2T, hA, N_NODES, 512, 512,
                                                     as2b, ad2b, asb, adb, 4);
  agg_fused<8><<<dim3(NG4), b256, 0, stream>>>(hA, off, csr_src, asb, adb, b2b, hB, 4);

  // ---- layer 3
  gemm_bf16<false, 1><<<dim3(G1), b256, 0, stream>>>(hB, W3T, hA, N_NODES, 128, 512,
                                                     as3b, ad3b, asb, adb, 1);
  agg_fused<2><<<dim3(NG4), b256, 0, stream>>>(hA, off, csr_src, asb, adb, b3b, hB, 1);

  // ---- merged mean-pool + FC
  pool_fc2<<<dim3(NUM_GRAPHS), b256, 0, stream>>>(hB, bat32, fcwb, fcbb, d_out, xu16);
}